// Round 2
// baseline (1170.137 us; speedup 1.0000x reference)
//
#include <hip/hip_runtime.h>

// Problem constants (fixed by reference setup_inputs)
#define BATCH 16
#define HH 64
#define WW 64
#define CC 1024
#define GG 32
#define CG 32          // channels per group
#define TH 8           // tile rows per block
#define TW 16          // tile cols per block
#define EPS 1e-3f
#define ALPHA 0.3f

// LDS: x halo tile 10*18*32 floats = 23 KB, reused for y tile 128*36 floats (18 KB)
#define XS_FLOATS ((TH + 2) * (TW + 2) * CG)   // 5760
#define YS_STRIDE 36                            // padded row stride for y[pixel][c]

// halo-row read: halo row (pr0+R), halo col (pcol+DX), channel quad c4
#define XLD(R, DX) (*(const float4*)(smem + (((pr0 + (R)) * (TW + 2)) + (pcol + (DX))) * CG + c4))
#define FMA4(A, X, K) \
    (A).x += (X).x * (K).x; (A).y += (X).y * (K).y; \
    (A).z += (X).z * (K).z; (A).w += (X).w * (K).w

#define PWACC(O, Y) \
    (O).x += (Y).x * w0.x + (Y).y * w1.x + (Y).z * w2.x + (Y).w * w3.x; \
    (O).y += (Y).x * w0.y + (Y).y * w1.y + (Y).z * w2.y + (Y).w * w3.y; \
    (O).z += (Y).x * w0.z + (Y).y * w1.z + (Y).z * w2.z + (Y).w * w3.z; \
    (O).w += (Y).x * w0.w + (Y).y * w1.w + (Y).z * w2.w + (Y).w * w3.w

#define BNLR(Z, O) \
    (Z).x = (O).x * sc.x + bi.x; (Z).x = ((Z).x >= 0.f) ? (Z).x : ALPHA * (Z).x; \
    (Z).y = (O).y * sc.y + bi.y; (Z).y = ((Z).y >= 0.f) ? (Z).y : ALPHA * (Z).y; \
    (Z).z = (O).z * sc.z + bi.z; (Z).z = ((Z).z >= 0.f) ? (Z).z : ALPHA * (Z).z; \
    (Z).w = (O).w * sc.w + bi.w; (Z).w = ((Z).w >= 0.f) ? (Z).w : ALPHA * (Z).w

__global__ __launch_bounds__(256, 4)
void fused_dw_pw_bn_lrelu(const float* __restrict__ x,
                          const float* __restrict__ dwk,   // (3,3,1,C)
                          const float* __restrict__ pwk,   // (G,Cg,Cg)
                          const float* __restrict__ gamma,
                          const float* __restrict__ beta,
                          const float* __restrict__ mmean,
                          const float* __restrict__ mvar,
                          float* __restrict__ out) {
    __shared__ float smem[XS_FLOATS];

    const int t = threadIdx.x;
    const int tilesW = WW / TW;                 // 4
    const int tile  = blockIdx.x;               // 0..31
    const int tw0   = (tile % tilesW) * TW;
    const int th0   = (tile / tilesW) * TH;
    const int g     = blockIdx.y;               // 0..31
    const int b     = blockIdx.z;               // 0..15
    const int cbase = g * CG;

    // ---------- phase 0: global -> LDS, x halo tile xs[r][col][c] ----------
    for (int i = t; i < (TH + 2) * (TW + 2) * 8; i += 256) {
        int q   = i & 7;                        // float4 index within 32 channels
        int pp  = i >> 3;                       // halo pixel position 0..179
        int r   = pp / (TW + 2);
        int col = pp % (TW + 2);
        int gh  = th0 - 1 + r;
        int gw  = tw0 - 1 + col;
        float4 v = make_float4(0.f, 0.f, 0.f, 0.f);
        if (gh >= 0 && gh < HH && gw >= 0 && gw < WW) {
            v = *(const float4*)(x + ((size_t)(b * HH + gh) * WW + gw) * CC + cbase + q * 4);
        }
        *(float4*)(smem + (size_t)pp * CG + q * 4) = v;
    }

    // ---------- depthwise taps, all NAMED registers (no arrays) ----------
    const int c4    = (t & 7) * 4;              // channel quad base within group
    const int pslot = t >> 3;                   // 0..31
    const int pcol  = pslot & 15;               // pixel column 0..15
    const int pr0   = (pslot >> 4) * 4;         // pixel row base: 0 or 4
    float4 k0 = *(const float4*)(dwk + 0 * CC + cbase + c4);
    float4 k1 = *(const float4*)(dwk + 1 * CC + cbase + c4);
    float4 k2 = *(const float4*)(dwk + 2 * CC + cbase + c4);
    float4 k3 = *(const float4*)(dwk + 3 * CC + cbase + c4);
    float4 k4 = *(const float4*)(dwk + 4 * CC + cbase + c4);
    float4 k5 = *(const float4*)(dwk + 5 * CC + cbase + c4);
    float4 k6 = *(const float4*)(dwk + 6 * CC + cbase + c4);
    float4 k7 = *(const float4*)(dwk + 7 * CC + cbase + c4);
    float4 k8 = *(const float4*)(dwk + 8 * CC + cbase + c4);

    __syncthreads();

    // ---------- phase 1: depthwise conv, rolling over 6 halo rows ----------
    // output i = tile row pr0+i; halo row R contributes with tap row dy = R - i
    float4 a0 = make_float4(0.f, 0.f, 0.f, 0.f);
    float4 a1 = a0, a2 = a0, a3 = a0;
    {   // halo row 0: dy=0 for a0
        float4 x0 = XLD(0, 0), x1 = XLD(0, 1), x2 = XLD(0, 2);
        FMA4(a0, x0, k0); FMA4(a0, x1, k1); FMA4(a0, x2, k2);
    }
    {   // halo row 1: dy=1 for a0, dy=0 for a1
        float4 x0 = XLD(1, 0), x1 = XLD(1, 1), x2 = XLD(1, 2);
        FMA4(a0, x0, k3); FMA4(a0, x1, k4); FMA4(a0, x2, k5);
        FMA4(a1, x0, k0); FMA4(a1, x1, k1); FMA4(a1, x2, k2);
    }
    {   // halo row 2
        float4 x0 = XLD(2, 0), x1 = XLD(2, 1), x2 = XLD(2, 2);
        FMA4(a0, x0, k6); FMA4(a0, x1, k7); FMA4(a0, x2, k8);
        FMA4(a1, x0, k3); FMA4(a1, x1, k4); FMA4(a1, x2, k5);
        FMA4(a2, x0, k0); FMA4(a2, x1, k1); FMA4(a2, x2, k2);
    }
    {   // halo row 3
        float4 x0 = XLD(3, 0), x1 = XLD(3, 1), x2 = XLD(3, 2);
        FMA4(a1, x0, k6); FMA4(a1, x1, k7); FMA4(a1, x2, k8);
        FMA4(a2, x0, k3); FMA4(a2, x1, k4); FMA4(a2, x2, k5);
        FMA4(a3, x0, k0); FMA4(a3, x1, k1); FMA4(a3, x2, k2);
    }
    {   // halo row 4
        float4 x0 = XLD(4, 0), x1 = XLD(4, 1), x2 = XLD(4, 2);
        FMA4(a2, x0, k6); FMA4(a2, x1, k7); FMA4(a2, x2, k8);
        FMA4(a3, x0, k3); FMA4(a3, x1, k4); FMA4(a3, x2, k5);
    }
    {   // halo row 5
        float4 x0 = XLD(5, 0), x1 = XLD(5, 1), x2 = XLD(5, 2);
        FMA4(a3, x0, k6); FMA4(a3, x1, k7); FMA4(a3, x2, k8);
    }

    __syncthreads();    // all xs reads done; safe to overwrite smem with y

    *(float4*)(smem + ((pr0 + 0) * TW + pcol) * YS_STRIDE + c4) = a0;
    *(float4*)(smem + ((pr0 + 1) * TW + pcol) * YS_STRIDE + c4) = a1;
    *(float4*)(smem + ((pr0 + 2) * TW + pcol) * YS_STRIDE + c4) = a2;
    *(float4*)(smem + ((pr0 + 3) * TW + pcol) * YS_STRIDE + c4) = a3;

    // ---------- BN constants for this thread's output-channel quad ----------
    const int d4  = (t & 7) * 4;                // output channel quad 0,4,..,28
    const int ps2 = t >> 3;                     // pixel slot 0..31
    float4 gm = *(const float4*)(gamma + cbase + d4);
    float4 bt = *(const float4*)(beta  + cbase + d4);
    float4 mm = *(const float4*)(mmean + cbase + d4);
    float4 mv = *(const float4*)(mvar  + cbase + d4);
    float4 sc, bi;
    sc.x = gm.x * rsqrtf(mv.x + EPS);  bi.x = bt.x - mm.x * sc.x;
    sc.y = gm.y * rsqrtf(mv.y + EPS);  bi.y = bt.y - mm.y * sc.y;
    sc.z = gm.z * rsqrtf(mv.z + EPS);  bi.z = bt.z - mm.z * sc.z;
    sc.w = gm.w * rsqrtf(mv.w + EPS);  bi.w = bt.w - mm.w * sc.w;

    __syncthreads();    // y tile visible

    // ---------- phase 2: pointwise, 4 pixels x 4 out-channels, NAMED accs ----------
    float4 o0 = make_float4(0.f, 0.f, 0.f, 0.f);
    float4 o1 = o0, o2 = o0, o3 = o0;
    const float* wg = pwk + (size_t)g * CG * CG;
    #pragma unroll
    for (int cq = 0; cq < 8; ++cq) {
        float4 w0 = *(const float4*)(wg + (cq * 4 + 0) * CG + d4);
        float4 w1 = *(const float4*)(wg + (cq * 4 + 1) * CG + d4);
        float4 w2 = *(const float4*)(wg + (cq * 4 + 2) * CG + d4);
        float4 w3 = *(const float4*)(wg + (cq * 4 + 3) * CG + d4);
        float4 ya = *(const float4*)(smem + (ps2 +  0) * YS_STRIDE + cq * 4);
        float4 yb = *(const float4*)(smem + (ps2 + 32) * YS_STRIDE + cq * 4);
        float4 yc = *(const float4*)(smem + (ps2 + 64) * YS_STRIDE + cq * 4);
        float4 yd = *(const float4*)(smem + (ps2 + 96) * YS_STRIDE + cq * 4);
        PWACC(o0, ya);
        PWACC(o1, yb);
        PWACC(o2, yc);
        PWACC(o3, yd);
    }

    // ---------- BN + LeakyReLU + coalesced float4 stores ----------
    {
        float4 z;
        int p, pr, pc;
        BNLR(z, o0);
        p = ps2 +  0; pr = p >> 4; pc = p & 15;
        *(float4*)(out + ((size_t)(b * HH + (th0 + pr)) * WW + (tw0 + pc)) * CC + cbase + d4) = z;
        BNLR(z, o1);
        p = ps2 + 32; pr = p >> 4; pc = p & 15;
        *(float4*)(out + ((size_t)(b * HH + (th0 + pr)) * WW + (tw0 + pc)) * CC + cbase + d4) = z;
        BNLR(z, o2);
        p = ps2 + 64; pr = p >> 4; pc = p & 15;
        *(float4*)(out + ((size_t)(b * HH + (th0 + pr)) * WW + (tw0 + pc)) * CC + cbase + d4) = z;
        BNLR(z, o3);
        p = ps2 + 96; pr = p >> 4; pc = p & 15;
        *(float4*)(out + ((size_t)(b * HH + (th0 + pr)) * WW + (tw0 + pc)) * CC + cbase + d4) = z;
    }
}

extern "C" void kernel_launch(void* const* d_in, const int* in_sizes, int n_in,
                              void* d_out, int out_size, void* d_ws, size_t ws_size,
                              hipStream_t stream) {
    const float* x     = (const float*)d_in[0];
    const float* dwk   = (const float*)d_in[1];
    const float* pwk   = (const float*)d_in[2];
    const float* gamma = (const float*)d_in[3];
    const float* beta  = (const float*)d_in[4];
    const float* mmean = (const float*)d_in[5];
    const float* mvar  = (const float*)d_in[6];
    float* out = (float*)d_out;

    dim3 grid((HH / TH) * (WW / TW), GG, BATCH);  // (32, 32, 16)
    dim3 block(256);
    hipLaunchKernelGGL(fused_dw_pw_bn_lrelu, grid, block, 0, stream,
                       x, dwk, pwk, gamma, beta, mmean, mvar, out);
}

// Round 3
// 619.785 us; speedup vs baseline: 1.8880x; 1.8880x over previous
//
#include <hip/hip_runtime.h>

// Problem constants (fixed by reference setup_inputs)
#define BATCH 16
#define HH 64
#define WW 64
#define CC 1024
#define GG 32
#define CG 32          // channels per group
#define TH 8           // tile rows per block
#define TW 16          // tile cols per block
#define EPS 1e-3f
#define ALPHA 0.3f

// LDS: x halo tile 10*18*32 floats = 23 KB, reused for y tile 128*36 floats (18 KB)
#define XS_FLOATS ((TH + 2) * (TW + 2) * CG)   // 5760
#define YS_STRIDE 36                            // padded row stride for y[pixel][c]

// halo-row read: halo row (pr0+R), halo col (pcol+DX), channel quad c4
#define XLD(R, DX) (*(const float4*)(smem + (((pr0 + (R)) * (TW + 2)) + (pcol + (DX))) * CG + c4))
#define FMA4(A, X, K) \
    (A).x += (X).x * (K).x; (A).y += (X).y * (K).y; \
    (A).z += (X).z * (K).z; (A).w += (X).w * (K).w

#define PWACC(O, Y) \
    (O).x += (Y).x * w0.x + (Y).y * w1.x + (Y).z * w2.x + (Y).w * w3.x; \
    (O).y += (Y).x * w0.y + (Y).y * w1.y + (Y).z * w2.y + (Y).w * w3.y; \
    (O).z += (Y).x * w0.z + (Y).y * w1.z + (Y).z * w2.z + (Y).w * w3.z; \
    (O).w += (Y).x * w0.w + (Y).y * w1.w + (Y).z * w2.w + (Y).w * w3.w

#define BNLR(Z, O) \
    (Z).x = (O).x * sc.x + bi.x; (Z).x = ((Z).x >= 0.f) ? (Z).x : ALPHA * (Z).x; \
    (Z).y = (O).y * sc.y + bi.y; (Z).y = ((Z).y >= 0.f) ? (Z).y : ALPHA * (Z).y; \
    (Z).z = (O).z * sc.z + bi.z; (Z).z = ((Z).z >= 0.f) ? (Z).z : ALPHA * (Z).z; \
    (Z).w = (O).w * sc.w + bi.w; (Z).w = ((Z).w >= 0.f) ? (Z).w : ALPHA * (Z).w

// max=4 waves/EU stops the scheduler from squeezing VGPRs to the 64-reg
// (8-wave) bucket -- that squeeze caused ~25-reg spills -> 1.6 GB of scratch
// writes in rounds 1/2. LDS caps us at 7 blocks/CU anyway, so >4 waves/EU
// is unreachable; min=2 gives the allocator headroom (256-reg budget).
__global__ __launch_bounds__(256) __attribute__((amdgpu_waves_per_eu(2, 4)))
void fused_dw_pw_bn_lrelu(const float* __restrict__ x,
                          const float* __restrict__ dwk,   // (3,3,1,C)
                          const float* __restrict__ pwk,   // (G,Cg,Cg)
                          const float* __restrict__ gamma,
                          const float* __restrict__ beta,
                          const float* __restrict__ mmean,
                          const float* __restrict__ mvar,
                          float* __restrict__ out) {
    __shared__ float smem[XS_FLOATS];

    const int t = threadIdx.x;
    const int tilesW = WW / TW;                 // 4
    const int tile  = blockIdx.x;               // 0..31
    const int tw0   = (tile % tilesW) * TW;
    const int th0   = (tile / tilesW) * TH;
    const int g     = blockIdx.y;               // 0..31
    const int b     = blockIdx.z;               // 0..15
    const int cbase = g * CG;

    // ---------- phase 0: global -> LDS, x halo tile xs[r][col][c] ----------
    for (int i = t; i < (TH + 2) * (TW + 2) * 8; i += 256) {
        int q   = i & 7;                        // float4 index within 32 channels
        int pp  = i >> 3;                       // halo pixel position 0..179
        int r   = pp / (TW + 2);
        int col = pp % (TW + 2);
        int gh  = th0 - 1 + r;
        int gw  = tw0 - 1 + col;
        float4 v = make_float4(0.f, 0.f, 0.f, 0.f);
        if (gh >= 0 && gh < HH && gw >= 0 && gw < WW) {
            v = *(const float4*)(x + ((size_t)(b * HH + gh) * WW + gw) * CC + cbase + q * 4);
        }
        *(float4*)(smem + (size_t)pp * CG + q * 4) = v;
    }

    // ---------- depthwise taps, all NAMED registers (no arrays) ----------
    const int c4    = (t & 7) * 4;              // channel quad base within group
    const int pslot = t >> 3;                   // 0..31
    const int pcol  = pslot & 15;               // pixel column 0..15
    const int pr0   = (pslot >> 4) * 4;         // pixel row base: 0 or 4
    float4 k0 = *(const float4*)(dwk + 0 * CC + cbase + c4);
    float4 k1 = *(const float4*)(dwk + 1 * CC + cbase + c4);
    float4 k2 = *(const float4*)(dwk + 2 * CC + cbase + c4);
    float4 k3 = *(const float4*)(dwk + 3 * CC + cbase + c4);
    float4 k4 = *(const float4*)(dwk + 4 * CC + cbase + c4);
    float4 k5 = *(const float4*)(dwk + 5 * CC + cbase + c4);
    float4 k6 = *(const float4*)(dwk + 6 * CC + cbase + c4);
    float4 k7 = *(const float4*)(dwk + 7 * CC + cbase + c4);
    float4 k8 = *(const float4*)(dwk + 8 * CC + cbase + c4);

    __syncthreads();

    // ---------- phase 1: depthwise conv, rolling over 6 halo rows ----------
    // output i = tile row pr0+i; halo row R contributes with tap row dy = R - i
    float4 a0 = make_float4(0.f, 0.f, 0.f, 0.f);
    float4 a1 = a0, a2 = a0, a3 = a0;
    {   // halo row 0: dy=0 for a0
        float4 x0 = XLD(0, 0), x1 = XLD(0, 1), x2 = XLD(0, 2);
        FMA4(a0, x0, k0); FMA4(a0, x1, k1); FMA4(a0, x2, k2);
    }
    {   // halo row 1: dy=1 for a0, dy=0 for a1
        float4 x0 = XLD(1, 0), x1 = XLD(1, 1), x2 = XLD(1, 2);
        FMA4(a0, x0, k3); FMA4(a0, x1, k4); FMA4(a0, x2, k5);
        FMA4(a1, x0, k0); FMA4(a1, x1, k1); FMA4(a1, x2, k2);
    }
    {   // halo row 2
        float4 x0 = XLD(2, 0), x1 = XLD(2, 1), x2 = XLD(2, 2);
        FMA4(a0, x0, k6); FMA4(a0, x1, k7); FMA4(a0, x2, k8);
        FMA4(a1, x0, k3); FMA4(a1, x1, k4); FMA4(a1, x2, k5);
        FMA4(a2, x0, k0); FMA4(a2, x1, k1); FMA4(a2, x2, k2);
    }
    {   // halo row 3
        float4 x0 = XLD(3, 0), x1 = XLD(3, 1), x2 = XLD(3, 2);
        FMA4(a1, x0, k6); FMA4(a1, x1, k7); FMA4(a1, x2, k8);
        FMA4(a2, x0, k3); FMA4(a2, x1, k4); FMA4(a2, x2, k5);
        FMA4(a3, x0, k0); FMA4(a3, x1, k1); FMA4(a3, x2, k2);
    }
    {   // halo row 4
        float4 x0 = XLD(4, 0), x1 = XLD(4, 1), x2 = XLD(4, 2);
        FMA4(a2, x0, k6); FMA4(a2, x1, k7); FMA4(a2, x2, k8);
        FMA4(a3, x0, k3); FMA4(a3, x1, k4); FMA4(a3, x2, k5);
    }
    {   // halo row 5
        float4 x0 = XLD(5, 0), x1 = XLD(5, 1), x2 = XLD(5, 2);
        FMA4(a3, x0, k6); FMA4(a3, x1, k7); FMA4(a3, x2, k8);
    }

    __syncthreads();    // all xs reads done; safe to overwrite smem with y

    *(float4*)(smem + ((pr0 + 0) * TW + pcol) * YS_STRIDE + c4) = a0;
    *(float4*)(smem + ((pr0 + 1) * TW + pcol) * YS_STRIDE + c4) = a1;
    *(float4*)(smem + ((pr0 + 2) * TW + pcol) * YS_STRIDE + c4) = a2;
    *(float4*)(smem + ((pr0 + 3) * TW + pcol) * YS_STRIDE + c4) = a3;

    // ---------- BN constants for this thread's output-channel quad ----------
    const int d4  = (t & 7) * 4;                // output channel quad 0,4,..,28
    const int ps2 = t >> 3;                     // pixel slot 0..31
    float4 gm = *(const float4*)(gamma + cbase + d4);
    float4 bt = *(const float4*)(beta  + cbase + d4);
    float4 mm = *(const float4*)(mmean + cbase + d4);
    float4 mv = *(const float4*)(mvar  + cbase + d4);
    float4 sc, bi;
    sc.x = gm.x * rsqrtf(mv.x + EPS);  bi.x = bt.x - mm.x * sc.x;
    sc.y = gm.y * rsqrtf(mv.y + EPS);  bi.y = bt.y - mm.y * sc.y;
    sc.z = gm.z * rsqrtf(mv.z + EPS);  bi.z = bt.z - mm.z * sc.z;
    sc.w = gm.w * rsqrtf(mv.w + EPS);  bi.w = bt.w - mm.w * sc.w;

    __syncthreads();    // y tile visible

    // ---------- phase 2: pointwise, 4 pixels x 4 out-channels, NAMED accs ----------
    float4 o0 = make_float4(0.f, 0.f, 0.f, 0.f);
    float4 o1 = o0, o2 = o0, o3 = o0;
    const float* wg = pwk + (size_t)g * CG * CG;
    #pragma unroll
    for (int cq = 0; cq < 8; ++cq) {
        float4 w0 = *(const float4*)(wg + (cq * 4 + 0) * CG + d4);
        float4 w1 = *(const float4*)(wg + (cq * 4 + 1) * CG + d4);
        float4 w2 = *(const float4*)(wg + (cq * 4 + 2) * CG + d4);
        float4 w3 = *(const float4*)(wg + (cq * 4 + 3) * CG + d4);
        float4 ya = *(const float4*)(smem + (ps2 +  0) * YS_STRIDE + cq * 4);
        float4 yb = *(const float4*)(smem + (ps2 + 32) * YS_STRIDE + cq * 4);
        float4 yc = *(const float4*)(smem + (ps2 + 64) * YS_STRIDE + cq * 4);
        float4 yd = *(const float4*)(smem + (ps2 + 96) * YS_STRIDE + cq * 4);
        PWACC(o0, ya);
        PWACC(o1, yb);
        PWACC(o2, yc);
        PWACC(o3, yd);
    }

    // ---------- BN + LeakyReLU + coalesced float4 stores ----------
    {
        float4 z;
        int p, pr, pc;
        BNLR(z, o0);
        p = ps2 +  0; pr = p >> 4; pc = p & 15;
        *(float4*)(out + ((size_t)(b * HH + (th0 + pr)) * WW + (tw0 + pc)) * CC + cbase + d4) = z;
        BNLR(z, o1);
        p = ps2 + 32; pr = p >> 4; pc = p & 15;
        *(float4*)(out + ((size_t)(b * HH + (th0 + pr)) * WW + (tw0 + pc)) * CC + cbase + d4) = z;
        BNLR(z, o2);
        p = ps2 + 64; pr = p >> 4; pc = p & 15;
        *(float4*)(out + ((size_t)(b * HH + (th0 + pr)) * WW + (tw0 + pc)) * CC + cbase + d4) = z;
        BNLR(z, o3);
        p = ps2 + 96; pr = p >> 4; pc = p & 15;
        *(float4*)(out + ((size_t)(b * HH + (th0 + pr)) * WW + (tw0 + pc)) * CC + cbase + d4) = z;
    }
}

extern "C" void kernel_launch(void* const* d_in, const int* in_sizes, int n_in,
                              void* d_out, int out_size, void* d_ws, size_t ws_size,
                              hipStream_t stream) {
    const float* x     = (const float*)d_in[0];
    const float* dwk   = (const float*)d_in[1];
    const float* pwk   = (const float*)d_in[2];
    const float* gamma = (const float*)d_in[3];
    const float* beta  = (const float*)d_in[4];
    const float* mmean = (const float*)d_in[5];
    const float* mvar  = (const float*)d_in[6];
    float* out = (float*)d_out;

    dim3 grid((HH / TH) * (WW / TW), GG, BATCH);  // (32, 32, 16)
    dim3 block(256);
    hipLaunchKernelGGL(fused_dw_pw_bn_lrelu, grid, block, 0, stream,
                       x, dwk, pwk, gamma, beta, mmean, mvar, out);
}